// Round 1
// baseline (433.038 us; speedup 1.0000x reference)
//
#include <hip/hip_runtime.h>
#include <hip/hip_bf16.h>
#include <stdint.h>

// Problem constants
#define N_TOK 8192
#define IN_DIM 1024
#define CDIM 512
#define NW 1536  // 3*CDIM stacked Wk,Wv,Wq

typedef short bf16x8 __attribute__((ext_vector_type(8)));
typedef float f32x4 __attribute__((ext_vector_type(4)));

__device__ __forceinline__ unsigned short f2bf(float f) {
  union { float f; unsigned int u; } x; x.f = f;
  unsigned int u = x.u;
  u += 0x7fffu + ((u >> 16) & 1u);   // round-to-nearest-even
  return (unsigned short)(u >> 16);
}

#define GLD16(g, l) __builtin_amdgcn_global_load_lds( \
    (const __attribute__((address_space(1))) void*)(g), \
    (__attribute__((address_space(3))) void*)(l), 16, 0, 0)

// ---------------------------------------------------------------------------
// K0: convert fp32 inputs -> bf16 staging buffers.
// Sb: (8192 x 1024) = concat(u,z); Wb: (1536 x 1024) = stack(Wk,Wv,Wq)
// ---------------------------------------------------------------------------
__global__ __launch_bounds__(256) void k_convert(
    const float* __restrict__ u, const float* __restrict__ z,
    const float* __restrict__ wk, const float* __restrict__ wv,
    const float* __restrict__ wq,
    ushort* __restrict__ Sb, ushort* __restrict__ Wb) {
  const int S4 = N_TOK * IN_DIM / 4;   // 2097152
  const int W4 = NW * IN_DIM / 4;      // 393216
  const int total = S4 + W4;
  for (int e = blockIdx.x * blockDim.x + threadIdx.x; e < total;
       e += gridDim.x * blockDim.x) {
    float4 v; ushort* dst;
    if (e < S4) {
      int idx = e << 2; int row = idx >> 10; int col = idx & 1023;
      const float* src = (col < 512) ? (u + row * 512 + col)
                                     : (z + row * 512 + (col - 512));
      v = *(const float4*)src;
      dst = Sb + idx;
    } else {
      int idx = (e - S4) << 2; int row = idx >> 10; int col = idx & 1023;
      const float* base = (row < 512) ? wk : (row < 1024 ? wv : wq);
      v = *(const float4*)(base + (size_t)(row & 511) * 1024 + col);
      dst = Wb + idx;
    }
    ushort4 o;
    o.x = f2bf(v.x); o.y = f2bf(v.y); o.z = f2bf(v.z); o.w = f2bf(v.w);
    *(ushort4*)dst = o;
  }
}

// ---------------------------------------------------------------------------
// K1: fused K/V/Q projection. bt-GEMM: out[i][n] = sum_k Sb[i][k]*Wb[n][k]
// 128x128 tile, BK=64, 4 waves (2x2), 4x4 16x16x32 frags per wave.
// Output routing: n<512 -> Kb row-major; 512..1023 -> VT transposed; else Qb.
// ---------------------------------------------------------------------------
__global__ __launch_bounds__(256) void k_kvq(
    const ushort* __restrict__ Sb, const ushort* __restrict__ Wb,
    const float* __restrict__ bk, const float* __restrict__ bv,
    const float* __restrict__ bq,
    ushort* __restrict__ Kb, ushort* __restrict__ Qb, ushort* __restrict__ VT) {
  __shared__ __align__(16) ushort As[128 * 64];
  __shared__ __align__(16) ushort Bs[128 * 64];
  const int tid = threadIdx.x, lane = tid & 63, w = tid >> 6;
  const int wr = w >> 1, wc = w & 1;
  const int tm = blockIdx.x, tn = blockIdx.y;

  f32x4 acc[4][4];
#pragma unroll
  for (int m = 0; m < 4; m++)
#pragma unroll
    for (int n = 0; n < 4; n++) acc[m][n] = (f32x4){0.f, 0.f, 0.f, 0.f};

  const ushort* ga0 = Sb + (size_t)tm * 128 * IN_DIM;
  const ushort* gb0 = Wb + (size_t)tn * 128 * IN_DIM;

  for (int k0 = 0; k0 < IN_DIM; k0 += 64) {
#pragma unroll
    for (int i = 0; i < 4; i++) {
      int e = i * 256 + tid;
      int row = e >> 3, c8 = (e & 7) << 3;
      GLD16(ga0 + (size_t)row * IN_DIM + k0 + c8, As + e * 8);
      GLD16(gb0 + (size_t)row * IN_DIM + k0 + c8, Bs + e * 8);
    }
    __syncthreads();
#pragma unroll
    for (int kb = 0; kb < 2; kb++) {
      bf16x8 af[4], bfr[4];
#pragma unroll
      for (int m = 0; m < 4; m++)
        af[m] = *(const bf16x8*)(As + (wr * 64 + m * 16 + (lane & 15)) * 64 +
                                 kb * 32 + ((lane >> 4) << 3));
#pragma unroll
      for (int n = 0; n < 4; n++)
        bfr[n] = *(const bf16x8*)(Bs + (wc * 64 + n * 16 + (lane & 15)) * 64 +
                                  kb * 32 + ((lane >> 4) << 3));
#pragma unroll
      for (int m = 0; m < 4; m++)
#pragma unroll
        for (int n = 0; n < 4; n++)
          acc[m][n] = __builtin_amdgcn_mfma_f32_16x16x32_bf16(af[m], bfr[n],
                                                              acc[m][n], 0, 0, 0);
    }
    __syncthreads();
  }

  // epilogue: C/D layout col=lane&15, row=4*(lane>>4)+reg
  const int region = tn >> 2;                 // 0=K 1=V 2=Q
  const int colr = (tn & 3) * 128 + wc * 64;  // + n*16 + (lane&15)
  const int rbase = tm * 128 + wr * 64;       // + m*16 + 4*(lane>>4) + reg
  const float* bias = (region == 0) ? bk : (region == 1 ? bv : bq);
  if (region == 1) {
#pragma unroll
    for (int m = 0; m < 4; m++) {
      int r0 = rbase + m * 16 + ((lane >> 4) << 2);
#pragma unroll
      for (int n = 0; n < 4; n++) {
        int c = colr + n * 16 + (lane & 15);
        float b = bias[c];
        ushort4 pk;
        pk.x = f2bf(acc[m][n][0] + b);
        pk.y = f2bf(acc[m][n][1] + b);
        pk.z = f2bf(acc[m][n][2] + b);
        pk.w = f2bf(acc[m][n][3] + b);
        *(ushort4*)(VT + (size_t)c * N_TOK + r0) = pk;  // transposed store
      }
    }
  } else {
    ushort* O = (region == 0) ? Kb : Qb;
#pragma unroll
    for (int m = 0; m < 4; m++) {
      int r0 = rbase + m * 16 + ((lane >> 4) << 2);
#pragma unroll
      for (int n = 0; n < 4; n++) {
        int c = colr + n * 16 + (lane & 15);
        float b = bias[c];
#pragma unroll
        for (int rg = 0; rg < 4; rg++)
          O[(size_t)(r0 + rg) * CDIM + c] = f2bf(acc[m][n][rg] + b);
      }
    }
  }
}

// ---------------------------------------------------------------------------
// K2: scores = Q @ K^T * (1/sqrt(512)); writes E = exp(score) (diag -> 0)
// into the attn output region, plus per-(row,tile) partial sums of E.
// Same 128x128 bt-GEMM structure, K=512.
// ---------------------------------------------------------------------------
__global__ __launch_bounds__(256) void k_scores(
    const ushort* __restrict__ Qb, const ushort* __restrict__ Kb,
    float* __restrict__ E, float* __restrict__ rowpart) {
  __shared__ __align__(16) ushort As[128 * 64];
  __shared__ __align__(16) ushort Bs[128 * 64];
  __shared__ float sums[256];
  const int tid = threadIdx.x, lane = tid & 63, w = tid >> 6;
  const int wr = w >> 1, wc = w & 1;
  const int tm = blockIdx.x, tn = blockIdx.y;

  f32x4 acc[4][4];
#pragma unroll
  for (int m = 0; m < 4; m++)
#pragma unroll
    for (int n = 0; n < 4; n++) acc[m][n] = (f32x4){0.f, 0.f, 0.f, 0.f};

  const ushort* ga0 = Qb + (size_t)tm * 128 * CDIM;
  const ushort* gb0 = Kb + (size_t)tn * 128 * CDIM;

  for (int k0 = 0; k0 < CDIM; k0 += 64) {
#pragma unroll
    for (int i = 0; i < 4; i++) {
      int e = i * 256 + tid;
      int row = e >> 3, c8 = (e & 7) << 3;
      GLD16(ga0 + (size_t)row * CDIM + k0 + c8, As + e * 8);
      GLD16(gb0 + (size_t)row * CDIM + k0 + c8, Bs + e * 8);
    }
    __syncthreads();
#pragma unroll
    for (int kb = 0; kb < 2; kb++) {
      bf16x8 af[4], bfr[4];
#pragma unroll
      for (int m = 0; m < 4; m++)
        af[m] = *(const bf16x8*)(As + (wr * 64 + m * 16 + (lane & 15)) * 64 +
                                 kb * 32 + ((lane >> 4) << 3));
#pragma unroll
      for (int n = 0; n < 4; n++)
        bfr[n] = *(const bf16x8*)(Bs + (wc * 64 + n * 16 + (lane & 15)) * 64 +
                                  kb * 32 + ((lane >> 4) << 3));
#pragma unroll
      for (int m = 0; m < 4; m++)
#pragma unroll
        for (int n = 0; n < 4; n++)
          acc[m][n] = __builtin_amdgcn_mfma_f32_16x16x32_bf16(af[m], bfr[n],
                                                              acc[m][n], 0, 0, 0);
    }
    __syncthreads();
  }

  const float scale = 0.044194173824159216f;  // 1/sqrt(512)
  float rs[4][4];
#pragma unroll
  for (int m = 0; m < 4; m++)
#pragma unroll
    for (int rg = 0; rg < 4; rg++) rs[m][rg] = 0.f;

#pragma unroll
  for (int m = 0; m < 4; m++) {
    int grow_b = tm * 128 + wr * 64 + m * 16 + ((lane >> 4) << 2);
#pragma unroll
    for (int n = 0; n < 4; n++) {
      int gcol = tn * 128 + wc * 64 + n * 16 + (lane & 15);
#pragma unroll
      for (int rg = 0; rg < 4; rg++) {
        int grow = grow_b + rg;
        float ev = (grow == gcol) ? 0.0f : __expf(acc[m][n][rg] * scale);
        E[(size_t)grow * N_TOK + gcol] = ev;
        rs[m][rg] += ev;
      }
    }
  }
  // butterfly over lane bits 0..3 -> sum over the wave's 64 columns
#pragma unroll
  for (int m = 0; m < 4; m++)
#pragma unroll
    for (int rg = 0; rg < 4; rg++) {
      float s = rs[m][rg];
      s += __shfl_xor(s, 1);
      s += __shfl_xor(s, 2);
      s += __shfl_xor(s, 4);
      s += __shfl_xor(s, 8);
      rs[m][rg] = s;
    }
  if ((lane & 15) == 0) {
#pragma unroll
    for (int m = 0; m < 4; m++)
#pragma unroll
      for (int rg = 0; rg < 4; rg++)
        sums[wc * 128 + wr * 64 + m * 16 + ((lane >> 4) << 2) + rg] = rs[m][rg];
  }
  __syncthreads();
  if (tid < 128)
    rowpart[(size_t)(tm * 128 + tid) * 64 + tn] = sums[tid] + sums[128 + tid];
}

// ---------------------------------------------------------------------------
// K2c: rcp_l[row] = 1 / sum_j E[row][j]  (from 64 tile partials)
// ---------------------------------------------------------------------------
__global__ __launch_bounds__(256) void k_rcp(const float* __restrict__ rowpart,
                                             float* __restrict__ rcp_l) {
  int row = blockIdx.x * blockDim.x + threadIdx.x;
  if (row < N_TOK) {
    const float4* p = (const float4*)(rowpart + (size_t)row * 64);
    float s = 0.f;
#pragma unroll
    for (int i = 0; i < 16; i++) {
      float4 v = p[i];
      s += v.x + v.y + v.z + v.w;
    }
    rcp_l[row] = 1.0f / s;
  }
}

// ---------------------------------------------------------------------------
// K3: normalize attn (in place) and accumulate partial m_bar = attn @ V.
// Row-block 64, 8 waves, each wave owns a 64x64 slice of m_bar columns.
// A (P tile) staged in LDS (XOR-swizzled); B frags read directly from VT
// (contiguous 16B along the contraction axis; L2/L3-resident).
// Grid: (128 row-blocks, 2 j-chunks). Partials summed by K4.
// ---------------------------------------------------------------------------
__global__ __launch_bounds__(512) void k_attn_pv(
    float* __restrict__ EA,            // exp-scores in, normalized attn out
    const ushort* __restrict__ VT, const float* __restrict__ rcp_l,
    float* __restrict__ part) {
  __shared__ __align__(16) ushort Ps[64 * 64];
  const int tid = threadIdx.x, lane = tid & 63, w = tid >> 6;  // 8 waves
  const int rb = blockIdx.x * 64;
  const int jc = blockIdx.y;
  const size_t jbase = (size_t)jc * 4096;

  f32x4 acc[4][4];
#pragma unroll
  for (int m = 0; m < 4; m++)
#pragma unroll
    for (int n = 0; n < 4; n++) acc[m][n] = (f32x4){0.f, 0.f, 0.f, 0.f};

  const int lrow = tid >> 3;  // 0..63
  const int tr = tid & 7;     // 8 threads per row, 8 floats each
  const float rl = rcp_l[rb + lrow];
  float* erow = EA + (size_t)(rb + lrow) * N_TOK + jbase + tr * 8;

  float4 e0 = *(const float4*)(erow);
  float4 e1 = *(const float4*)(erow + 4);

  for (int jt = 0; jt < 64; ++jt) {
    float4 p0, p1;
    p0.x = e0.x * rl; p0.y = e0.y * rl; p0.z = e0.z * rl; p0.w = e0.w * rl;
    p1.x = e1.x * rl; p1.y = e1.y * rl; p1.z = e1.z * rl; p1.w = e1.w * rl;
    *(float4*)(erow + jt * 64) = p0;
    *(float4*)(erow + jt * 64 + 4) = p1;
    bf16x8 pb;
    pb[0] = (short)f2bf(p0.x); pb[1] = (short)f2bf(p0.y);
    pb[2] = (short)f2bf(p0.z); pb[3] = (short)f2bf(p0.w);
    pb[4] = (short)f2bf(p1.x); pb[5] = (short)f2bf(p1.y);
    pb[6] = (short)f2bf(p1.z); pb[7] = (short)f2bf(p1.w);

    // B fragments straight from global VT (independent of LDS state)
    bf16x8 bfr[2][4];
#pragma unroll
    for (int kb = 0; kb < 2; kb++)
#pragma unroll
      for (int n = 0; n < 4; n++)
        bfr[kb][n] = *(const bf16x8*)(VT +
            (size_t)(w * 64 + n * 16 + (lane & 15)) * N_TOK + jbase +
            jt * 64 + kb * 32 + ((lane >> 4) << 3));

    __syncthreads();  // previous iteration's Ps reads done
    {
      int chunk = tr ^ (lrow & 7);  // XOR swizzle (16B granules)
      *(bf16x8*)(Ps + lrow * 64 + chunk * 8) = pb;
    }
    __syncthreads();

    // prefetch next E tile under the MFMA cluster
    if (jt < 63) {
      e0 = *(const float4*)(erow + (jt + 1) * 64);
      e1 = *(const float4*)(erow + (jt + 1) * 64 + 4);
    }

#pragma unroll
    for (int kb = 0; kb < 2; kb++) {
      bf16x8 af[4];
#pragma unroll
      for (int m = 0; m < 4; m++) {
        int r = m * 16 + (lane & 15);
        int chunk = (kb * 4 + (lane >> 4)) ^ (r & 7);
        af[m] = *(const bf16x8*)(Ps + r * 64 + chunk * 8);
      }
#pragma unroll
      for (int m = 0; m < 4; m++)
#pragma unroll
        for (int n = 0; n < 4; n++)
          acc[m][n] = __builtin_amdgcn_mfma_f32_16x16x32_bf16(af[m], bfr[kb][n],
                                                              acc[m][n], 0, 0, 0);
    }
  }

  float* P = part + (size_t)jc * N_TOK * CDIM;
#pragma unroll
  for (int m = 0; m < 4; m++) {
    int r0 = rb + m * 16 + ((lane >> 4) << 2);
#pragma unroll
    for (int n = 0; n < 4; n++) {
      int c = w * 64 + n * 16 + (lane & 15);
#pragma unroll
      for (int rg = 0; rg < 4; rg++)
        P[(size_t)(r0 + rg) * CDIM + c] = acc[m][n][rg];
    }
  }
}

// ---------------------------------------------------------------------------
// K4: m_bar = part[0] + part[1]
// ---------------------------------------------------------------------------
__global__ __launch_bounds__(256) void k_reduce(const float* __restrict__ part,
                                                float* __restrict__ mbar) {
  int idx4 = blockIdx.x * blockDim.x + threadIdx.x;
  const int T4 = N_TOK * CDIM / 4;
  if (idx4 < T4) {
    float4 a = ((const float4*)part)[idx4];
    float4 b = ((const float4*)(part + (size_t)N_TOK * CDIM))[idx4];
    float4 o;
    o.x = a.x + b.x; o.y = a.y + b.y; o.z = a.z + b.z; o.w = a.w + b.w;
    ((float4*)mbar)[idx4] = o;
  }
}

// ---------------------------------------------------------------------------
extern "C" void kernel_launch(void* const* d_in, const int* in_sizes, int n_in,
                              void* d_out, int out_size, void* d_ws,
                              size_t ws_size, hipStream_t stream) {
  const float* u  = (const float*)d_in[0];
  const float* z  = (const float*)d_in[1];
  const float* Wk = (const float*)d_in[2];
  const float* bk = (const float*)d_in[3];
  const float* Wv = (const float*)d_in[4];
  const float* bv = (const float*)d_in[5];
  const float* Wq = (const float*)d_in[6];
  const float* bq = (const float*)d_in[7];

  float* mbar = (float*)d_out;
  float* attn = (float*)d_out + (size_t)N_TOK * CDIM;

  char* ws = (char*)d_ws;
  // workspace layout (bytes); total needed = 47,218,688
  ushort* Sb     = (ushort*)(ws + 0);          // 16,777,216
  ushort* Wb     = (ushort*)(ws + 16777216);   //  3,145,728
  ushort* Kb     = (ushort*)(ws + 19922944);   //  8,388,608
  ushort* Qb     = (ushort*)(ws + 28311552);   //  8,388,608
  float*  part   = (float*)(ws + 0);           // 33,554,432 (overlaps Sb..Qb; used after K2)
  ushort* VT     = (ushort*)(ws + 36700160);   //  8,388,608
  float*  rcp_l  = (float*)(ws + 45088768);    //     32,768
  float*  rowpart= (float*)(ws + 45121536);    //  2,097,152

  k_convert<<<dim3(2048), dim3(256), 0, stream>>>(u, z, Wk, Wv, Wq, Sb, Wb);
  k_kvq<<<dim3(64, 12), dim3(256), 0, stream>>>(Sb, Wb, bk, bv, bq, Kb, Qb, VT);
  k_scores<<<dim3(64, 64), dim3(256), 0, stream>>>(Qb, Kb, attn, rowpart);
  k_rcp<<<dim3(32), dim3(256), 0, stream>>>(rowpart, rcp_l);
  k_attn_pv<<<dim3(128, 2), dim3(512), 0, stream>>>(attn, VT, rcp_l, part);
  k_reduce<<<dim3(4096), dim3(256), 0, stream>>>(part, mbar);
}

// Round 2
// 408.125 us; speedup vs baseline: 1.0610x; 1.0610x over previous
//
#include <hip/hip_runtime.h>
#include <hip/hip_bf16.h>
#include <stdint.h>

// Problem constants
#define N_TOK 8192
#define IN_DIM 1024
#define CDIM 512
#define NW 1536  // 3*CDIM stacked Wk,Wv,Wq

typedef short bf16x8 __attribute__((ext_vector_type(8)));
typedef float f32x4 __attribute__((ext_vector_type(4)));

__device__ __forceinline__ unsigned short f2bf(float f) {
  union { float f; unsigned int u; } x; x.f = f;
  unsigned int u = x.u;
  u += 0x7fffu + ((u >> 16) & 1u);   // round-to-nearest-even
  return (unsigned short)(u >> 16);
}
__device__ __forceinline__ float bf2f(unsigned short us) {
  union { unsigned int u; float f; } x; x.u = ((unsigned int)us) << 16;
  return x.f;
}

#define GLD16(g, l) __builtin_amdgcn_global_load_lds( \
    (const __attribute__((address_space(1))) void*)(g), \
    (__attribute__((address_space(3))) void*)(l), 16, 0, 0)

// ---------------------------------------------------------------------------
// K0: convert fp32 inputs -> bf16 staging buffers.
// Sb: (8192 x 1024) = concat(u,z); Wb: (1536 x 1024) = stack(Wk,Wv,Wq)
// ---------------------------------------------------------------------------
__global__ __launch_bounds__(256) void k_convert(
    const float* __restrict__ u, const float* __restrict__ z,
    const float* __restrict__ wk, const float* __restrict__ wv,
    const float* __restrict__ wq,
    ushort* __restrict__ Sb, ushort* __restrict__ Wb) {
  const int S4 = N_TOK * IN_DIM / 4;   // 2097152
  const int W4 = NW * IN_DIM / 4;      // 393216
  const int total = S4 + W4;
  for (int e = blockIdx.x * blockDim.x + threadIdx.x; e < total;
       e += gridDim.x * blockDim.x) {
    float4 v; ushort* dst;
    if (e < S4) {
      int idx = e << 2; int row = idx >> 10; int col = idx & 1023;
      const float* src = (col < 512) ? (u + row * 512 + col)
                                     : (z + row * 512 + (col - 512));
      v = *(const float4*)src;
      dst = Sb + idx;
    } else {
      int idx = (e - S4) << 2; int row = idx >> 10; int col = idx & 1023;
      const float* base = (row < 512) ? wk : (row < 1024 ? wv : wq);
      v = *(const float4*)(base + (size_t)(row & 511) * 1024 + col);
      dst = Wb + idx;
    }
    ushort4 o;
    o.x = f2bf(v.x); o.y = f2bf(v.y); o.z = f2bf(v.z); o.w = f2bf(v.w);
    *(ushort4*)dst = o;
  }
}

// ---------------------------------------------------------------------------
// K1: fused K/V/Q projection. bt-GEMM: out[i][n] = sum_k Sb[i][k]*Wb[n][k]
// 128x128 tile, BK=64, 4 waves (2x2), 4x4 16x16x32 frags per wave.
// Output routing: n<512 -> Kb row-major; 512..1023 -> VT transposed; else Qb.
// ---------------------------------------------------------------------------
__global__ __launch_bounds__(256) void k_kvq(
    const ushort* __restrict__ Sb, const ushort* __restrict__ Wb,
    const float* __restrict__ bk, const float* __restrict__ bv,
    const float* __restrict__ bq,
    ushort* __restrict__ Kb, ushort* __restrict__ Qb, ushort* __restrict__ VT) {
  __shared__ __align__(16) ushort As[128 * 64];
  __shared__ __align__(16) ushort Bs[128 * 64];
  const int tid = threadIdx.x, lane = tid & 63, w = tid >> 6;
  const int wr = w >> 1, wc = w & 1;
  const int tm = blockIdx.x, tn = blockIdx.y;

  f32x4 acc[4][4];
#pragma unroll
  for (int m = 0; m < 4; m++)
#pragma unroll
    for (int n = 0; n < 4; n++) acc[m][n] = (f32x4){0.f, 0.f, 0.f, 0.f};

  const ushort* ga0 = Sb + (size_t)tm * 128 * IN_DIM;
  const ushort* gb0 = Wb + (size_t)tn * 128 * IN_DIM;

  for (int k0 = 0; k0 < IN_DIM; k0 += 64) {
#pragma unroll
    for (int i = 0; i < 4; i++) {
      int ce = i * 256 + tid;
      int row = ce >> 3, c8 = (ce & 7) << 3;
      GLD16(ga0 + (size_t)row * IN_DIM + k0 + c8, As + ce * 8);
      GLD16(gb0 + (size_t)row * IN_DIM + k0 + c8, Bs + ce * 8);
    }
    __syncthreads();
#pragma unroll
    for (int kb = 0; kb < 2; kb++) {
      bf16x8 af[4], bfr[4];
#pragma unroll
      for (int m = 0; m < 4; m++)
        af[m] = *(const bf16x8*)(As + (wr * 64 + m * 16 + (lane & 15)) * 64 +
                                 kb * 32 + ((lane >> 4) << 3));
#pragma unroll
      for (int n = 0; n < 4; n++)
        bfr[n] = *(const bf16x8*)(Bs + (wc * 64 + n * 16 + (lane & 15)) * 64 +
                                  kb * 32 + ((lane >> 4) << 3));
#pragma unroll
      for (int m = 0; m < 4; m++)
#pragma unroll
        for (int n = 0; n < 4; n++)
          acc[m][n] = __builtin_amdgcn_mfma_f32_16x16x32_bf16(af[m], bfr[n],
                                                              acc[m][n], 0, 0, 0);
    }
    __syncthreads();
  }

  // epilogue: C/D layout col=lane&15, row=4*(lane>>4)+reg
  const int region = tn >> 2;                 // 0=K 1=V 2=Q
  const int colr = (tn & 3) * 128 + wc * 64;  // + n*16 + (lane&15)
  const int rbase = tm * 128 + wr * 64;       // + m*16 + 4*(lane>>4) + reg
  const float* bias = (region == 0) ? bk : (region == 1 ? bv : bq);
  if (region == 1) {
#pragma unroll
    for (int m = 0; m < 4; m++) {
      int r0 = rbase + m * 16 + ((lane >> 4) << 2);
#pragma unroll
      for (int n = 0; n < 4; n++) {
        int c = colr + n * 16 + (lane & 15);
        float b = bias[c];
        ushort4 pk;
        pk.x = f2bf(acc[m][n][0] + b);
        pk.y = f2bf(acc[m][n][1] + b);
        pk.z = f2bf(acc[m][n][2] + b);
        pk.w = f2bf(acc[m][n][3] + b);
        *(ushort4*)(VT + (size_t)c * N_TOK + r0) = pk;  // transposed store
      }
    }
  } else {
    ushort* O = (region == 0) ? Kb : Qb;
#pragma unroll
    for (int m = 0; m < 4; m++) {
      int r0 = rbase + m * 16 + ((lane >> 4) << 2);
#pragma unroll
      for (int n = 0; n < 4; n++) {
        int c = colr + n * 16 + (lane & 15);
        float b = bias[c];
#pragma unroll
        for (int rg = 0; rg < 4; rg++)
          O[(size_t)(r0 + rg) * CDIM + c] = f2bf(acc[m][n][rg] + b);
      }
    }
  }
}

// ---------------------------------------------------------------------------
// K2: scores = Q @ K^T * (1/sqrt(512)); writes E = bf16(exp(score)) (diag->0)
// plus per-(row,tile) partial sums of the bf16-rounded E (self-consistent
// with what k_norm / k_pv consume).
// ---------------------------------------------------------------------------
__global__ __launch_bounds__(256) void k_scores(
    const ushort* __restrict__ Qb, const ushort* __restrict__ Kb,
    ushort* __restrict__ E, float* __restrict__ rowpart) {
  __shared__ __align__(16) ushort As[128 * 64];
  __shared__ __align__(16) ushort Bs[128 * 64];
  __shared__ float sums[256];
  const int tid = threadIdx.x, lane = tid & 63, w = tid >> 6;
  const int wr = w >> 1, wc = w & 1;
  const int tm = blockIdx.x, tn = blockIdx.y;

  f32x4 acc[4][4];
#pragma unroll
  for (int m = 0; m < 4; m++)
#pragma unroll
    for (int n = 0; n < 4; n++) acc[m][n] = (f32x4){0.f, 0.f, 0.f, 0.f};

  const ushort* ga0 = Qb + (size_t)tm * 128 * CDIM;
  const ushort* gb0 = Kb + (size_t)tn * 128 * CDIM;

  for (int k0 = 0; k0 < CDIM; k0 += 64) {
#pragma unroll
    for (int i = 0; i < 4; i++) {
      int ce = i * 256 + tid;
      int row = ce >> 3, c8 = (ce & 7) << 3;
      GLD16(ga0 + (size_t)row * CDIM + k0 + c8, As + ce * 8);
      GLD16(gb0 + (size_t)row * CDIM + k0 + c8, Bs + ce * 8);
    }
    __syncthreads();
#pragma unroll
    for (int kb = 0; kb < 2; kb++) {
      bf16x8 af[4], bfr[4];
#pragma unroll
      for (int m = 0; m < 4; m++)
        af[m] = *(const bf16x8*)(As + (wr * 64 + m * 16 + (lane & 15)) * 64 +
                                 kb * 32 + ((lane >> 4) << 3));
#pragma unroll
      for (int n = 0; n < 4; n++)
        bfr[n] = *(const bf16x8*)(Bs + (wc * 64 + n * 16 + (lane & 15)) * 64 +
                                  kb * 32 + ((lane >> 4) << 3));
#pragma unroll
      for (int m = 0; m < 4; m++)
#pragma unroll
        for (int n = 0; n < 4; n++)
          acc[m][n] = __builtin_amdgcn_mfma_f32_16x16x32_bf16(af[m], bfr[n],
                                                              acc[m][n], 0, 0, 0);
    }
    __syncthreads();
  }

  const float scale = 0.044194173824159216f;  // 1/sqrt(512)
  float rs[4][4];
#pragma unroll
  for (int m = 0; m < 4; m++)
#pragma unroll
    for (int rg = 0; rg < 4; rg++) rs[m][rg] = 0.f;

#pragma unroll
  for (int m = 0; m < 4; m++) {
    int grow_b = tm * 128 + wr * 64 + m * 16 + ((lane >> 4) << 2);
#pragma unroll
    for (int n = 0; n < 4; n++) {
      int gcol = tn * 128 + wc * 64 + n * 16 + (lane & 15);
#pragma unroll
      for (int rg = 0; rg < 4; rg++) {
        int grow = grow_b + rg;
        float ev = (grow == gcol) ? 0.0f : __expf(acc[m][n][rg] * scale);
        unsigned short evb = f2bf(ev);
        E[(size_t)grow * N_TOK + gcol] = evb;
        rs[m][rg] += bf2f(evb);
      }
    }
  }
  // butterfly over lane bits 0..3 -> sum over the wave's 64 columns
#pragma unroll
  for (int m = 0; m < 4; m++)
#pragma unroll
    for (int rg = 0; rg < 4; rg++) {
      float s = rs[m][rg];
      s += __shfl_xor(s, 1);
      s += __shfl_xor(s, 2);
      s += __shfl_xor(s, 4);
      s += __shfl_xor(s, 8);
      rs[m][rg] = s;
    }
  if ((lane & 15) == 0) {
#pragma unroll
    for (int m = 0; m < 4; m++)
#pragma unroll
      for (int rg = 0; rg < 4; rg++)
        sums[wc * 128 + wr * 64 + m * 16 + ((lane >> 4) << 2) + rg] = rs[m][rg];
  }
  __syncthreads();
  if (tid < 128)
    rowpart[(size_t)(tm * 128 + tid) * 64 + tn] = sums[tid] + sums[128 + tid];
}

// ---------------------------------------------------------------------------
// K2c: rcp_l[row] = 1 / sum_j E[row][j]  (from 64 tile partials)
// ---------------------------------------------------------------------------
__global__ __launch_bounds__(256) void k_rcp(const float* __restrict__ rowpart,
                                             float* __restrict__ rcp_l) {
  int row = blockIdx.x * blockDim.x + threadIdx.x;
  if (row < N_TOK) {
    const float4* p = (const float4*)(rowpart + (size_t)row * 64);
    float s = 0.f;
#pragma unroll
    for (int i = 0; i < 16; i++) {
      float4 v = p[i];
      s += v.x + v.y + v.z + v.w;
    }
    rcp_l[row] = 1.0f / s;
  }
}

// ---------------------------------------------------------------------------
// K3: m_bar = (E @ V) * rcp_l  -- pure bt-GEMM, M=8192 N=512 K=8192.
// BM=128, BN=64, BK=64; 4 waves (2x2); per wave 4x2 16x16 frags.
// A = E (bf16, lda=8192), B = VT (512x8192 row-major = V^T).
// Grid (64, 8) = 512 blocks -> 2 blocks/CU.
// ---------------------------------------------------------------------------
__global__ __launch_bounds__(256) void k_pv(
    const ushort* __restrict__ E, const ushort* __restrict__ VT,
    const float* __restrict__ rcp_l, float* __restrict__ mbar) {
  __shared__ __align__(16) ushort As[128 * 64];
  __shared__ __align__(16) ushort Bs[64 * 64];
  const int tid = threadIdx.x, lane = tid & 63, w = tid >> 6;
  const int wr = w >> 1, wc = w & 1;
  const int tm = blockIdx.x, tn = blockIdx.y;

  f32x4 acc[4][2];
#pragma unroll
  for (int m = 0; m < 4; m++)
#pragma unroll
    for (int n = 0; n < 2; n++) acc[m][n] = (f32x4){0.f, 0.f, 0.f, 0.f};

  const ushort* ga0 = E + (size_t)tm * 128 * N_TOK;
  const ushort* gb0 = VT + (size_t)tn * 64 * N_TOK;

  for (int k0 = 0; k0 < N_TOK; k0 += 64) {
#pragma unroll
    for (int i = 0; i < 4; i++) {
      int ce = i * 256 + tid;
      int row = ce >> 3, c8 = (ce & 7) << 3;
      GLD16(ga0 + (size_t)row * N_TOK + k0 + c8, As + ce * 8);
    }
#pragma unroll
    for (int i = 0; i < 2; i++) {
      int ce = i * 256 + tid;
      int row = ce >> 3, c8 = (ce & 7) << 3;
      GLD16(gb0 + (size_t)row * N_TOK + k0 + c8, Bs + ce * 8);
    }
    __syncthreads();
#pragma unroll
    for (int kb = 0; kb < 2; kb++) {
      bf16x8 af[4], bfr[2];
#pragma unroll
      for (int m = 0; m < 4; m++)
        af[m] = *(const bf16x8*)(As + (wr * 64 + m * 16 + (lane & 15)) * 64 +
                                 kb * 32 + ((lane >> 4) << 3));
#pragma unroll
      for (int n = 0; n < 2; n++)
        bfr[n] = *(const bf16x8*)(Bs + (wc * 32 + n * 16 + (lane & 15)) * 64 +
                                  kb * 32 + ((lane >> 4) << 3));
#pragma unroll
      for (int m = 0; m < 4; m++)
#pragma unroll
        for (int n = 0; n < 2; n++)
          acc[m][n] = __builtin_amdgcn_mfma_f32_16x16x32_bf16(af[m], bfr[n],
                                                              acc[m][n], 0, 0, 0);
    }
    __syncthreads();
  }

#pragma unroll
  for (int m = 0; m < 4; m++) {
    int r0 = tm * 128 + wr * 64 + m * 16 + ((lane >> 4) << 2);
#pragma unroll
    for (int n = 0; n < 2; n++) {
      int c = tn * 64 + wc * 32 + n * 16 + (lane & 15);
#pragma unroll
      for (int rg = 0; rg < 4; rg++)
        mbar[(size_t)(r0 + rg) * CDIM + c] = acc[m][n][rg] * rcp_l[r0 + rg];
    }
  }
}

// ---------------------------------------------------------------------------
// K4: attn[row][j] = float(E[row][j]) * rcp_l[row]   for rows [row0, row0+nrows)
// Vectorized: 8 elems per thread (16B read, 32B write).
// ---------------------------------------------------------------------------
__global__ __launch_bounds__(256) void k_norm(
    const ushort* __restrict__ E, float* __restrict__ attn,
    const float* __restrict__ rcp_l, int row0, int nrows) {
  const int units = nrows << 10;  // 1024 8-elem units per row
  for (int uidx = blockIdx.x * blockDim.x + threadIdx.x; uidx < units;
       uidx += gridDim.x * blockDim.x) {
    int row = row0 + (uidx >> 10);
    int c8 = (uidx & 1023) << 3;
    const float rl = rcp_l[row];
    uint4 ev = *(const uint4*)(E + ((size_t)row << 13) + c8);
    float4 o0, o1;
    o0.x = bf2f((unsigned short)(ev.x & 0xffffu)) * rl;
    o0.y = bf2f((unsigned short)(ev.x >> 16)) * rl;
    o0.z = bf2f((unsigned short)(ev.y & 0xffffu)) * rl;
    o0.w = bf2f((unsigned short)(ev.y >> 16)) * rl;
    o1.x = bf2f((unsigned short)(ev.z & 0xffffu)) * rl;
    o1.y = bf2f((unsigned short)(ev.z >> 16)) * rl;
    o1.z = bf2f((unsigned short)(ev.w & 0xffffu)) * rl;
    o1.w = bf2f((unsigned short)(ev.w >> 16)) * rl;
    float* op = attn + ((size_t)row << 13) + c8;
    *(float4*)op = o0;
    *(float4*)(op + 4) = o1;
  }
}

// ---------------------------------------------------------------------------
// K4b (tail-mode only): last row (8191). Its fp32 write range overlaps its own
// bf16 E source, so read the whole row into registers first, sync, then write.
// Single block of 256 threads; 32 cols per thread.
// ---------------------------------------------------------------------------
__global__ __launch_bounds__(256) void k_lastrow(
    const ushort* __restrict__ E, float* __restrict__ attn,
    const float* __restrict__ rcp_l) {
  const int row = N_TOK - 1;
  const int t = threadIdx.x;
  const float rl = rcp_l[row];
  const uint4* src = (const uint4*)(E + ((size_t)row << 13)) + t * 4;
  uint4 r0 = src[0], r1 = src[1], r2 = src[2], r3 = src[3];
  __syncthreads();
  float* dst = attn + ((size_t)row << 13) + t * 32;
  uint4 rr[4] = {r0, r1, r2, r3};
#pragma unroll
  for (int q = 0; q < 4; q++) {
    float4 o0, o1;
    o0.x = bf2f((unsigned short)(rr[q].x & 0xffffu)) * rl;
    o0.y = bf2f((unsigned short)(rr[q].x >> 16)) * rl;
    o0.z = bf2f((unsigned short)(rr[q].y & 0xffffu)) * rl;
    o0.w = bf2f((unsigned short)(rr[q].y >> 16)) * rl;
    o1.x = bf2f((unsigned short)(rr[q].z & 0xffffu)) * rl;
    o1.y = bf2f((unsigned short)(rr[q].z >> 16)) * rl;
    o1.z = bf2f((unsigned short)(rr[q].w & 0xffffu)) * rl;
    o1.w = bf2f((unsigned short)(rr[q].w >> 16)) * rl;
    *(float4*)(dst + q * 8) = o0;
    *(float4*)(dst + q * 8 + 4) = o1;
  }
}

// ---------------------------------------------------------------------------
extern "C" void kernel_launch(void* const* d_in, const int* in_sizes, int n_in,
                              void* d_out, int out_size, void* d_ws,
                              size_t ws_size, hipStream_t stream) {
  const float* u  = (const float*)d_in[0];
  const float* z  = (const float*)d_in[1];
  const float* Wk = (const float*)d_in[2];
  const float* bk = (const float*)d_in[3];
  const float* Wv = (const float*)d_in[4];
  const float* bv = (const float*)d_in[5];
  const float* Wq = (const float*)d_in[6];
  const float* bq = (const float*)d_in[7];

  float* mbar = (float*)d_out;
  float* attn = (float*)d_out + (size_t)N_TOK * CDIM;

  char* ws = (char*)d_ws;
  // workspace layout (bytes)
  ushort* Kb      = (ushort*)(ws + 0);          //  8,388,608
  ushort* Qb      = (ushort*)(ws + 8388608);    //  8,388,608
  ushort* VT      = (ushort*)(ws + 16777216);   //  8,388,608
  float*  rcp_l   = (float*)(ws + 25165824);    //     32,768
  float*  rowpart = (float*)(ws + 25198592);    //  2,097,152
  ushort* Sb      = (ushort*)(ws + 27295744);   // 16,777,216 (dead after k_kvq)
  ushort* Wb      = (ushort*)(ws + 44072960);   //  3,145,728 (dead after k_kvq)
  // E (bf16, 134,217,728 B): workspace if it fits (reuses Sb/Wb region),
  // else the upper half of the attn output region with phased normalize.
  const size_t E_WS_OFF = 27295744;
  const size_t REQ = E_WS_OFF + 134217728;  // 161,513,472
  const bool ws_mode = (ws_size >= REQ);
  ushort* E = ws_mode ? (ushort*)(ws + E_WS_OFF)
                      : (ushort*)((char*)attn + 134217728);

  k_convert<<<dim3(2048), dim3(256), 0, stream>>>(u, z, Wk, Wv, Wq, Sb, Wb);
  k_kvq<<<dim3(64, 12), dim3(256), 0, stream>>>(Sb, Wb, bk, bv, bq, Kb, Qb, VT);
  k_scores<<<dim3(64, 64), dim3(256), 0, stream>>>(Qb, Kb, E, rowpart);
  k_rcp<<<dim3(32), dim3(256), 0, stream>>>(rowpart, rcp_l);
  k_pv<<<dim3(64, 8), dim3(256), 0, stream>>>(E, VT, rcp_l, mbar);

  if (ws_mode) {
    k_norm<<<dim3(2048), dim3(256), 0, stream>>>(E, attn, rcp_l, 0, N_TOK);
  } else {
    // Phased in-place expansion: range [a,b) writes fp32 over bytes that only
    // cover E rows < a (b <= (a+8192)/2), which are already consumed.
    static const int ph[] = {0, 4096, 6144, 7168, 7680, 7936, 8064, 8128,
                             8160, 8176, 8184, 8188, 8190, 8191};
    for (int p = 0; p + 1 < (int)(sizeof(ph) / sizeof(ph[0])); ++p) {
      int a = ph[p], b = ph[p + 1];
      int units = (b - a) << 10;
      int blocks = (units + 255) / 256;
      if (blocks > 2048) blocks = 2048;
      k_norm<<<dim3(blocks), dim3(256), 0, stream>>>(E, attn, rcp_l, a, b - a);
    }
    k_lastrow<<<dim3(1), dim3(256), 0, stream>>>(E, attn, rcp_l);
  }
}

// Round 3
// 398.822 us; speedup vs baseline: 1.0858x; 1.0233x over previous
//
#include <hip/hip_runtime.h>
#include <hip/hip_bf16.h>
#include <stdint.h>

// Problem constants
#define N_TOK 8192
#define IN_DIM 1024
#define CDIM 512
#define NW 1536  // 3*CDIM stacked Wk,Wv,Wq

typedef short bf16x8 __attribute__((ext_vector_type(8)));
typedef float f32x4 __attribute__((ext_vector_type(4)));

__device__ __forceinline__ unsigned short f2bf(float f) {
  union { float f; unsigned int u; } x; x.f = f;
  unsigned int u = x.u;
  u += 0x7fffu + ((u >> 16) & 1u);   // round-to-nearest-even
  return (unsigned short)(u >> 16);
}
__device__ __forceinline__ float bf2f(unsigned short us) {
  union { unsigned int u; float f; } x; x.u = ((unsigned int)us) << 16;
  return x.f;
}

#define GLD16(g, l) __builtin_amdgcn_global_load_lds( \
    (const __attribute__((address_space(1))) void*)(g), \
    (__attribute__((address_space(3))) void*)(l), 16, 0, 0)

// ---------------------------------------------------------------------------
// K0: convert fp32 inputs -> bf16 staging buffers.
// Sb: (8192 x 1024) = concat(u,z); Wb: (1536 x 1024) = stack(Wk,Wv,Wq)
// ---------------------------------------------------------------------------
__global__ __launch_bounds__(256) void k_convert(
    const float* __restrict__ u, const float* __restrict__ z,
    const float* __restrict__ wk, const float* __restrict__ wv,
    const float* __restrict__ wq,
    ushort* __restrict__ Sb, ushort* __restrict__ Wb) {
  const int S4 = N_TOK * IN_DIM / 4;   // 2097152
  const int W4 = NW * IN_DIM / 4;      // 393216
  const int total = S4 + W4;
  for (int e = blockIdx.x * blockDim.x + threadIdx.x; e < total;
       e += gridDim.x * blockDim.x) {
    float4 v; ushort* dst;
    if (e < S4) {
      int idx = e << 2; int row = idx >> 10; int col = idx & 1023;
      const float* src = (col < 512) ? (u + row * 512 + col)
                                     : (z + row * 512 + (col - 512));
      v = *(const float4*)src;
      dst = Sb + idx;
    } else {
      int idx = (e - S4) << 2; int row = idx >> 10; int col = idx & 1023;
      const float* base = (row < 512) ? wk : (row < 1024 ? wv : wq);
      v = *(const float4*)(base + (size_t)(row & 511) * 1024 + col);
      dst = Wb + idx;
    }
    ushort4 o;
    o.x = f2bf(v.x); o.y = f2bf(v.y); o.z = f2bf(v.z); o.w = f2bf(v.w);
    *(ushort4*)dst = o;
  }
}

// ---------------------------------------------------------------------------
// K1: fused K/V/Q projection. bt-GEMM: out[i][n] = sum_k Sb[i][k]*Wb[n][k]
// 128x128 tile, BK=64, 4 waves (2x2), 4x4 16x16x32 frags per wave.
// Output routing: n<512 -> Kb row-major; 512..1023 -> VT transposed; else Qb.
// ---------------------------------------------------------------------------
__global__ __launch_bounds__(256) void k_kvq(
    const ushort* __restrict__ Sb, const ushort* __restrict__ Wb,
    const float* __restrict__ bk, const float* __restrict__ bv,
    const float* __restrict__ bq,
    ushort* __restrict__ Kb, ushort* __restrict__ Qb, ushort* __restrict__ VT) {
  __shared__ __align__(16) ushort As[128 * 64];
  __shared__ __align__(16) ushort Bs[128 * 64];
  const int tid = threadIdx.x, lane = tid & 63, w = tid >> 6;
  const int wr = w >> 1, wc = w & 1;
  const int tm = blockIdx.x, tn = blockIdx.y;

  f32x4 acc[4][4];
#pragma unroll
  for (int m = 0; m < 4; m++)
#pragma unroll
    for (int n = 0; n < 4; n++) acc[m][n] = (f32x4){0.f, 0.f, 0.f, 0.f};

  const ushort* ga0 = Sb + (size_t)tm * 128 * IN_DIM;
  const ushort* gb0 = Wb + (size_t)tn * 128 * IN_DIM;

  for (int k0 = 0; k0 < IN_DIM; k0 += 64) {
#pragma unroll
    for (int i = 0; i < 4; i++) {
      int ce = i * 256 + tid;
      int row = ce >> 3, c8 = (ce & 7) << 3;
      GLD16(ga0 + (size_t)row * IN_DIM + k0 + c8, As + ce * 8);
      GLD16(gb0 + (size_t)row * IN_DIM + k0 + c8, Bs + ce * 8);
    }
    __syncthreads();
#pragma unroll
    for (int kb = 0; kb < 2; kb++) {
      bf16x8 af[4], bfr[4];
#pragma unroll
      for (int m = 0; m < 4; m++)
        af[m] = *(const bf16x8*)(As + (wr * 64 + m * 16 + (lane & 15)) * 64 +
                                 kb * 32 + ((lane >> 4) << 3));
#pragma unroll
      for (int n = 0; n < 4; n++)
        bfr[n] = *(const bf16x8*)(Bs + (wc * 64 + n * 16 + (lane & 15)) * 64 +
                                  kb * 32 + ((lane >> 4) << 3));
#pragma unroll
      for (int m = 0; m < 4; m++)
#pragma unroll
        for (int n = 0; n < 4; n++)
          acc[m][n] = __builtin_amdgcn_mfma_f32_16x16x32_bf16(af[m], bfr[n],
                                                              acc[m][n], 0, 0, 0);
    }
    __syncthreads();
  }

  // epilogue: C/D layout col=lane&15, row=4*(lane>>4)+reg
  const int region = tn >> 2;                 // 0=K 1=V 2=Q
  const int colr = (tn & 3) * 128 + wc * 64;  // + n*16 + (lane&15)
  const int rbase = tm * 128 + wr * 64;       // + m*16 + 4*(lane>>4) + reg
  const float* bias = (region == 0) ? bk : (region == 1 ? bv : bq);
  if (region == 1) {
#pragma unroll
    for (int m = 0; m < 4; m++) {
      int r0 = rbase + m * 16 + ((lane >> 4) << 2);
#pragma unroll
      for (int n = 0; n < 4; n++) {
        int c = colr + n * 16 + (lane & 15);
        float b = bias[c];
        ushort4 pk;
        pk.x = f2bf(acc[m][n][0] + b);
        pk.y = f2bf(acc[m][n][1] + b);
        pk.z = f2bf(acc[m][n][2] + b);
        pk.w = f2bf(acc[m][n][3] + b);
        *(ushort4*)(VT + (size_t)c * N_TOK + r0) = pk;  // transposed store
      }
    }
  } else {
    ushort* O = (region == 0) ? Kb : Qb;
#pragma unroll
    for (int m = 0; m < 4; m++) {
      int r0 = rbase + m * 16 + ((lane >> 4) << 2);
#pragma unroll
      for (int n = 0; n < 4; n++) {
        int c = colr + n * 16 + (lane & 15);
        float b = bias[c];
#pragma unroll
        for (int rg = 0; rg < 4; rg++)
          O[(size_t)(r0 + rg) * CDIM + c] = f2bf(acc[m][n][rg] + b);
      }
    }
  }
}

// ---------------------------------------------------------------------------
// K2: scores = Q @ K^T * (1/sqrt(512)); writes E = bf16(exp(score)) (diag->0)
// plus per-(row,tile) partial sums of the bf16-rounded E (self-consistent
// with what downstream consumes).
// ---------------------------------------------------------------------------
__global__ __launch_bounds__(256) void k_scores(
    const ushort* __restrict__ Qb, const ushort* __restrict__ Kb,
    ushort* __restrict__ E, float* __restrict__ rowpart) {
  __shared__ __align__(16) ushort As[128 * 64];
  __shared__ __align__(16) ushort Bs[128 * 64];
  __shared__ float sums[256];
  const int tid = threadIdx.x, lane = tid & 63, w = tid >> 6;
  const int wr = w >> 1, wc = w & 1;
  const int tm = blockIdx.x, tn = blockIdx.y;

  f32x4 acc[4][4];
#pragma unroll
  for (int m = 0; m < 4; m++)
#pragma unroll
    for (int n = 0; n < 4; n++) acc[m][n] = (f32x4){0.f, 0.f, 0.f, 0.f};

  const ushort* ga0 = Qb + (size_t)tm * 128 * CDIM;
  const ushort* gb0 = Kb + (size_t)tn * 128 * CDIM;

  for (int k0 = 0; k0 < CDIM; k0 += 64) {
#pragma unroll
    for (int i = 0; i < 4; i++) {
      int ce = i * 256 + tid;
      int row = ce >> 3, c8 = (ce & 7) << 3;
      GLD16(ga0 + (size_t)row * CDIM + k0 + c8, As + ce * 8);
      GLD16(gb0 + (size_t)row * CDIM + k0 + c8, Bs + ce * 8);
    }
    __syncthreads();
#pragma unroll
    for (int kb = 0; kb < 2; kb++) {
      bf16x8 af[4], bfr[4];
#pragma unroll
      for (int m = 0; m < 4; m++)
        af[m] = *(const bf16x8*)(As + (wr * 64 + m * 16 + (lane & 15)) * 64 +
                                 kb * 32 + ((lane >> 4) << 3));
#pragma unroll
      for (int n = 0; n < 4; n++)
        bfr[n] = *(const bf16x8*)(Bs + (wc * 64 + n * 16 + (lane & 15)) * 64 +
                                  kb * 32 + ((lane >> 4) << 3));
#pragma unroll
      for (int m = 0; m < 4; m++)
#pragma unroll
        for (int n = 0; n < 4; n++)
          acc[m][n] = __builtin_amdgcn_mfma_f32_16x16x32_bf16(af[m], bfr[n],
                                                              acc[m][n], 0, 0, 0);
    }
    __syncthreads();
  }

  const float scale = 0.044194173824159216f;  // 1/sqrt(512)
  float rs[4][4];
#pragma unroll
  for (int m = 0; m < 4; m++)
#pragma unroll
    for (int rg = 0; rg < 4; rg++) rs[m][rg] = 0.f;

#pragma unroll
  for (int m = 0; m < 4; m++) {
    int grow_b = tm * 128 + wr * 64 + m * 16 + ((lane >> 4) << 2);
#pragma unroll
    for (int n = 0; n < 4; n++) {
      int gcol = tn * 128 + wc * 64 + n * 16 + (lane & 15);
#pragma unroll
      for (int rg = 0; rg < 4; rg++) {
        int grow = grow_b + rg;
        float ev = (grow == gcol) ? 0.0f : __expf(acc[m][n][rg] * scale);
        unsigned short evb = f2bf(ev);
        E[(size_t)grow * N_TOK + gcol] = evb;
        rs[m][rg] += bf2f(evb);
      }
    }
  }
  // butterfly over lane bits 0..3 -> sum over the wave's 64 columns
#pragma unroll
  for (int m = 0; m < 4; m++)
#pragma unroll
    for (int rg = 0; rg < 4; rg++) {
      float s = rs[m][rg];
      s += __shfl_xor(s, 1);
      s += __shfl_xor(s, 2);
      s += __shfl_xor(s, 4);
      s += __shfl_xor(s, 8);
      rs[m][rg] = s;
    }
  if ((lane & 15) == 0) {
#pragma unroll
    for (int m = 0; m < 4; m++)
#pragma unroll
      for (int rg = 0; rg < 4; rg++)
        sums[wc * 128 + wr * 64 + m * 16 + ((lane >> 4) << 2) + rg] = rs[m][rg];
  }
  __syncthreads();
  if (tid < 128)
    rowpart[(size_t)(tm * 128 + tid) * 64 + tn] = sums[tid] + sums[128 + tid];
}

// ---------------------------------------------------------------------------
// K2c: rcp_l[row] = 1 / sum_j E[row][j]  (from 64 tile partials)
// ---------------------------------------------------------------------------
__global__ __launch_bounds__(256) void k_rcp(const float* __restrict__ rowpart,
                                             float* __restrict__ rcp_l) {
  int row = blockIdx.x * blockDim.x + threadIdx.x;
  if (row < N_TOK) {
    const float4* p = (const float4*)(rowpart + (size_t)row * 64);
    float s = 0.f;
#pragma unroll
    for (int i = 0; i < 16; i++) {
      float4 v = p[i];
      s += v.x + v.y + v.z + v.w;
    }
    rcp_l[row] = 1.0f / s;
  }
}

// ---------------------------------------------------------------------------
// K3: m_bar = (E @ V) * rcp_l  -- bt-GEMM, M=8192 N=512 K=8192 — WITH the
// attn normalize+write fused in: block (tm,tn) owns attn cols
// [tn*1024,(tn+1)*1024) for its 128 rows; during the 16 K-steps inside that
// range it re-reads the just-staged (L2-hot) E lines, scales by rcp_l, and
// writes coalesced fp32 attn. Spread evenly over all 512 blocks, overlapped
// under MFMA. `attn` may be null (fallback mode) -> pure GEMM.
// BM=128, BN=64, BK=64; 4 waves (2x2); per wave 4x2 16x16 frags.
// Grid (64, 8) = 512 blocks -> 2 blocks/CU.
// ---------------------------------------------------------------------------
__global__ __launch_bounds__(256) void k_pv_norm(
    const ushort* __restrict__ E, const ushort* __restrict__ VT,
    const float* __restrict__ rcp_l, float* __restrict__ mbar,
    float* __restrict__ attn) {
  __shared__ __align__(16) ushort As[128 * 64];
  __shared__ __align__(16) ushort Bs[64 * 64];
  const int tid = threadIdx.x, lane = tid & 63, w = tid >> 6;
  const int wr = w >> 1, wc = w & 1;
  const int tm = blockIdx.x, tn = blockIdx.y;

  f32x4 acc[4][2];
#pragma unroll
  for (int m = 0; m < 4; m++)
#pragma unroll
    for (int n = 0; n < 2; n++) acc[m][n] = (f32x4){0.f, 0.f, 0.f, 0.f};

  const ushort* ga0 = E + (size_t)tm * 128 * N_TOK;
  const ushort* gb0 = VT + (size_t)tn * 64 * N_TOK;
  const int kw_lo = tn << 10;          // this block's attn column range
  const int kw_hi = kw_lo + 1024;

  for (int k0 = 0; k0 < N_TOK; k0 += 64) {
#pragma unroll
    for (int i = 0; i < 4; i++) {
      int ce = i * 256 + tid;
      int row = ce >> 3, c8 = (ce & 7) << 3;
      GLD16(ga0 + (size_t)row * N_TOK + k0 + c8, As + ce * 8);
    }
#pragma unroll
    for (int i = 0; i < 2; i++) {
      int ce = i * 256 + tid;
      int row = ce >> 3, c8 = (ce & 7) << 3;
      GLD16(gb0 + (size_t)row * N_TOK + k0 + c8, Bs + ce * 8);
    }
    __syncthreads();
#pragma unroll
    for (int kb = 0; kb < 2; kb++) {
      bf16x8 af[4], bfr[2];
#pragma unroll
      for (int m = 0; m < 4; m++)
        af[m] = *(const bf16x8*)(As + (wr * 64 + m * 16 + (lane & 15)) * 64 +
                                 kb * 32 + ((lane >> 4) << 3));
#pragma unroll
      for (int n = 0; n < 2; n++)
        bfr[n] = *(const bf16x8*)(Bs + (wc * 32 + n * 16 + (lane & 15)) * 64 +
                                  kb * 32 + ((lane >> 4) << 3));
#pragma unroll
      for (int m = 0; m < 4; m++)
#pragma unroll
        for (int n = 0; n < 2; n++)
          acc[m][n] = __builtin_amdgcn_mfma_f32_16x16x32_bf16(af[m], bfr[n],
                                                              acc[m][n], 0, 0, 0);
    }

    // fused attn write: 128 rows x 64 cols fp32, 4 passes of 32 rows.
    // Reads E from global (L2-hot: global_load_lds fetched these lines above).
    if (attn != nullptr && k0 >= kw_lo && k0 < kw_hi) {
#pragma unroll
      for (int p = 0; p < 4; p++) {
        int ce = p * 256 + tid;            // 0..1023
        int row = ce >> 3;                 // 0..127
        int c8 = (ce & 7) << 3;            // 0..56
        int grow = tm * 128 + row;
        float rl = rcp_l[grow];
        uint4 ev = *(const uint4*)(E + ((size_t)grow << 13) + k0 + c8);
        float4 o0, o1;
        o0.x = bf2f((unsigned short)(ev.x & 0xffffu)) * rl;
        o0.y = bf2f((unsigned short)(ev.x >> 16)) * rl;
        o0.z = bf2f((unsigned short)(ev.y & 0xffffu)) * rl;
        o0.w = bf2f((unsigned short)(ev.y >> 16)) * rl;
        o1.x = bf2f((unsigned short)(ev.z & 0xffffu)) * rl;
        o1.y = bf2f((unsigned short)(ev.z >> 16)) * rl;
        o1.z = bf2f((unsigned short)(ev.w & 0xffffu)) * rl;
        o1.w = bf2f((unsigned short)(ev.w >> 16)) * rl;
        float* op = attn + ((size_t)grow << 13) + k0 + c8;
        *(float4*)op = o0;
        *(float4*)(op + 4) = o1;
      }
    }
    __syncthreads();
  }

#pragma unroll
  for (int m = 0; m < 4; m++) {
    int r0 = tm * 128 + wr * 64 + m * 16 + ((lane >> 4) << 2);
#pragma unroll
    for (int n = 0; n < 2; n++) {
      int c = tn * 64 + wc * 32 + n * 16 + (lane & 15);
#pragma unroll
      for (int rg = 0; rg < 4; rg++)
        mbar[(size_t)(r0 + rg) * CDIM + c] = acc[m][n][rg] * rcp_l[r0 + rg];
    }
  }
}

// ---------------------------------------------------------------------------
// K4 (fallback only): attn[row][j] = float(E[row][j]) * rcp_l[row]
// ---------------------------------------------------------------------------
__global__ __launch_bounds__(256) void k_norm(
    const ushort* __restrict__ E, float* __restrict__ attn,
    const float* __restrict__ rcp_l, int row0, int nrows) {
  const int units = nrows << 10;  // 1024 8-elem units per row
  for (int uidx = blockIdx.x * blockDim.x + threadIdx.x; uidx < units;
       uidx += gridDim.x * blockDim.x) {
    int row = row0 + (uidx >> 10);
    int c8 = (uidx & 1023) << 3;
    const float rl = rcp_l[row];
    uint4 ev = *(const uint4*)(E + ((size_t)row << 13) + c8);
    float4 o0, o1;
    o0.x = bf2f((unsigned short)(ev.x & 0xffffu)) * rl;
    o0.y = bf2f((unsigned short)(ev.x >> 16)) * rl;
    o0.z = bf2f((unsigned short)(ev.y & 0xffffu)) * rl;
    o0.w = bf2f((unsigned short)(ev.y >> 16)) * rl;
    o1.x = bf2f((unsigned short)(ev.z & 0xffffu)) * rl;
    o1.y = bf2f((unsigned short)(ev.z >> 16)) * rl;
    o1.z = bf2f((unsigned short)(ev.w & 0xffffu)) * rl;
    o1.w = bf2f((unsigned short)(ev.w >> 16)) * rl;
    float* op = attn + ((size_t)row << 13) + c8;
    *(float4*)op = o0;
    *(float4*)(op + 4) = o1;
  }
}

// ---------------------------------------------------------------------------
// K4b (fallback only): last row (8191) — fp32 write range overlaps its own
// bf16 E source; read whole row to regs first.
// ---------------------------------------------------------------------------
__global__ __launch_bounds__(256) void k_lastrow(
    const ushort* __restrict__ E, float* __restrict__ attn,
    const float* __restrict__ rcp_l) {
  const int row = N_TOK - 1;
  const int t = threadIdx.x;
  const float rl = rcp_l[row];
  const uint4* src = (const uint4*)(E + ((size_t)row << 13)) + t * 4;
  uint4 rr[4] = {src[0], src[1], src[2], src[3]};
  __syncthreads();
  float* dst = attn + ((size_t)row << 13) + t * 32;
#pragma unroll
  for (int q = 0; q < 4; q++) {
    float4 o0, o1;
    o0.x = bf2f((unsigned short)(rr[q].x & 0xffffu)) * rl;
    o0.y = bf2f((unsigned short)(rr[q].x >> 16)) * rl;
    o0.z = bf2f((unsigned short)(rr[q].y & 0xffffu)) * rl;
    o0.w = bf2f((unsigned short)(rr[q].y >> 16)) * rl;
    o1.x = bf2f((unsigned short)(rr[q].z & 0xffffu)) * rl;
    o1.y = bf2f((unsigned short)(rr[q].z >> 16)) * rl;
    o1.z = bf2f((unsigned short)(rr[q].w & 0xffffu)) * rl;
    o1.w = bf2f((unsigned short)(rr[q].w >> 16)) * rl;
    *(float4*)(dst + q * 8) = o0;
    *(float4*)(dst + q * 8 + 4) = o1;
  }
}

// ---------------------------------------------------------------------------
extern "C" void kernel_launch(void* const* d_in, const int* in_sizes, int n_in,
                              void* d_out, int out_size, void* d_ws,
                              size_t ws_size, hipStream_t stream) {
  const float* u  = (const float*)d_in[0];
  const float* z  = (const float*)d_in[1];
  const float* Wk = (const float*)d_in[2];
  const float* bk = (const float*)d_in[3];
  const float* Wv = (const float*)d_in[4];
  const float* bv = (const float*)d_in[5];
  const float* Wq = (const float*)d_in[6];
  const float* bq = (const float*)d_in[7];

  float* mbar = (float*)d_out;
  float* attn = (float*)d_out + (size_t)N_TOK * CDIM;

  char* ws = (char*)d_ws;
  // workspace layout (bytes)
  ushort* Kb      = (ushort*)(ws + 0);          //  8,388,608
  ushort* Qb      = (ushort*)(ws + 8388608);    //  8,388,608
  ushort* VT      = (ushort*)(ws + 16777216);   //  8,388,608
  float*  rcp_l   = (float*)(ws + 25165824);    //     32,768
  float*  rowpart = (float*)(ws + 25198592);    //  2,097,152
  ushort* Sb      = (ushort*)(ws + 27295744);   // 16,777,216 (dead after k_kvq)
  ushort* Wb      = (ushort*)(ws + 44072960);   //  3,145,728 (dead after k_kvq)
  // E (bf16, 134,217,728 B): workspace if it fits (reuses Sb/Wb region),
  // else the upper half of the attn output region with phased normalize.
  const size_t E_WS_OFF = 27295744;
  const size_t REQ = E_WS_OFF + 134217728;  // 161,513,472
  const bool ws_mode = (ws_size >= REQ);
  ushort* E = ws_mode ? (ushort*)(ws + E_WS_OFF)
                      : (ushort*)((char*)attn + 134217728);

  k_convert<<<dim3(2048), dim3(256), 0, stream>>>(u, z, Wk, Wv, Wq, Sb, Wb);
  k_kvq<<<dim3(64, 12), dim3(256), 0, stream>>>(Sb, Wb, bk, bv, bq, Kb, Qb, VT);
  k_scores<<<dim3(64, 64), dim3(256), 0, stream>>>(Qb, Kb, E, rowpart);
  k_rcp<<<dim3(32), dim3(256), 0, stream>>>(rowpart, rcp_l);
  k_pv_norm<<<dim3(64, 8), dim3(256), 0, stream>>>(E, VT, rcp_l, mbar,
                                                   ws_mode ? attn : nullptr);

  if (!ws_mode) {
    // Phased in-place expansion: range [a,b) writes fp32 over bytes that only
    // cover E rows < a (b <= (a+8192)/2), which are already consumed.
    static const int ph[] = {0, 4096, 6144, 7168, 7680, 7936, 8064, 8128,
                             8160, 8176, 8184, 8188, 8190, 8191};
    for (int p = 0; p + 1 < (int)(sizeof(ph) / sizeof(ph[0])); ++p) {
      int a = ph[p], b = ph[p + 1];
      int units = (b - a) << 10;
      int blocks = (units + 255) / 256;
      if (blocks > 2048) blocks = 2048;
      k_norm<<<dim3(blocks), dim3(256), 0, stream>>>(E, attn, rcp_l, a, b - a);
    }
    k_lastrow<<<dim3(1), dim3(256), 0, stream>>>(E, attn, rcp_l);
  }
}